// Round 9
// baseline (481.937 us; speedup 1.0000x reference)
//
#include <hip/hip_runtime.h>
#include <hip/hip_bf16.h>
#include <math.h>

#define FIN  1433
#define HID  16
#define NCLS 7
#define BM   128
#define BK   32
#define KS   4
#define NREP 4                 // scatter replica count (== KS, reuses slice buffers)
#define KT_TOTAL 45            // ceil(1433/32)
#define KPAD (KT_TOTAL * BK)   // 1440

typedef __attribute__((ext_vector_type(8))) short bf16x8;
typedef __attribute__((ext_vector_type(4))) float f32x4;

__device__ inline float bf2f(ushort u) {
  unsigned int t = ((unsigned int)u) << 16;
  return __uint_as_float(t);
}
__device__ inline ushort f2bf(float f) {
  __hip_bfloat16 h = __float2bfloat16(f);
  return *(ushort*)&h;
}
// HW packed bf16 atomic add: mem[addr] (2x bf16) += data (2x bf16).
__device__ inline void pk_atomic_bf16(void* addr, unsigned int data) {
  asm volatile("global_atomic_pk_add_bf16 %0, %1, off"
               :: "v"((unsigned long long)addr), "v"(data) : "memory");
}

// W prep: wT[c][k] bf16 (row stride KPAD); c<16 -> w_rel1, c>=16 -> w_root1.
__global__ __launch_bounds__(256) void k_wt(
    const float* __restrict__ w_root, const float* __restrict__ w_rel,
    ushort* __restrict__ wT) {
  int idx = blockIdx.x * 256 + threadIdx.x;
  if (idx >= 32 * KPAD) return;
  int c = idx / KPAD, k = idx % KPAD;
  float v = 0.f;
  if (k < FIN) v = (c < HID) ? w_rel[k * HID + c] : w_root[k * HID + (c - HID)];
  wT[idx] = f2bf(v);
}

// K1: split-K MFMA dual GEMM; outputs bf16 partials (p = x@w_rel, a = x@w_root [+b]).
__global__ __launch_bounds__(256) void k1_mfma(
    const float* __restrict__ x, const ushort* __restrict__ wT,
    const float* __restrict__ b_rel,
    ushort* __restrict__ pbase, ushort* __restrict__ abase,
    size_t seg, int n) {
  __shared__ ushort xs[2][BM * BK];
  __shared__ ushort wsh[2][32 * BK];

  const int tid  = threadIdx.x;
  const int lane = tid & 63;
  const int wave = tid >> 6;
  const int row0 = blockIdx.x * BM;
  const int slice = blockIdx.y;
  const int kt_beg = (KT_TOTAL * slice) / KS;
  const int kt_end = (KT_TOTAL * (slice + 1)) / KS;

  f32x4 acc[2][2] = {};

  const int sr  = tid >> 5;
  const int sk  = tid & 31;
  const int wc  = tid >> 3;
  const int wt4 = tid & 7;

  float  xr[16];
  ushort4 wr;

  auto load_tile = [&](int kt) {
    const int k0 = kt * BK;
    const int gk = k0 + sk;
    const bool kv = gk < FIN;
#pragma unroll
    for (int i = 0; i < 16; ++i) {
      int gr = row0 + i * 8 + sr;
      xr[i] = (gr < n && kv) ? x[(size_t)gr * FIN + gk] : 0.f;
    }
    wr = *(const ushort4*)&wT[(size_t)wc * KPAD + k0 + wt4 * 4];
  };

  auto store_stage = [&](int b) {
#pragma unroll
    for (int i = 0; i < 16; ++i)
      xs[b][(i * 8 + sr) * BK + sk] = f2bf(xr[i]);
    *(ushort4*)&wsh[b][wc * BK + wt4 * 4] = wr;
  };

  const int m = lane & 15, o = lane >> 4;

  auto do_mfma = [&](int b) {
    bf16x8 b0 = *(const bf16x8*)&wsh[b][(m)      * BK + o * 8];
    bf16x8 b1 = *(const bf16x8*)&wsh[b][(16 + m) * BK + o * 8];
#pragma unroll
    for (int mf = 0; mf < 2; ++mf) {
      bf16x8 a = *(const bf16x8*)&xs[b][(wave * 32 + mf * 16 + m) * BK + o * 8];
      acc[mf][0] = __builtin_amdgcn_mfma_f32_16x16x32_bf16(a, b0, acc[mf][0], 0, 0, 0);
      acc[mf][1] = __builtin_amdgcn_mfma_f32_16x16x32_bf16(a, b1, acc[mf][1], 0, 0, 0);
    }
  };

  load_tile(kt_beg);
  store_stage(0);
  __syncthreads();
  for (int t = kt_beg; t < kt_end; ++t) {
    const int b = (t - kt_beg) & 1;
    const bool more = (t + 1) < kt_end;
    if (more) load_tile(t + 1);
    do_mfma(b);
    if (more) store_stage(b ^ 1);
    __syncthreads();
  }

  ushort* __restrict__ p_out = pbase + (size_t)slice * seg;
  ushort* __restrict__ a_out = abase + (size_t)slice * seg;
  const float bv = (slice == 0) ? b_rel[m] : 0.f;
#pragma unroll
  for (int mf = 0; mf < 2; ++mf) {
#pragma unroll
    for (int j = 0; j < 4; ++j) {
      int gr = row0 + wave * 32 + mf * 16 + o * 4 + j;
      if (gr < n) {
        p_out[(size_t)gr * HID + m] = f2bf(acc[mf][0][j]);
        a_out[(size_t)gr * HID + m] = f2bf(acc[mf][1][j] + bv);
      }
    }
  }
}

// KR: sum KS bf16 partials into slice 0; ZERO abase slices 1..3 (they become
// the scatter replica buffers).
__global__ __launch_bounds__(256) void k_reduce(
    ushort* __restrict__ pbase, ushort* __restrict__ abase,
    size_t seg, int n8) {
  int i = blockIdx.x * 256 + threadIdx.x;
  if (i >= n8) return;
  float ps[8], as[8];
#pragma unroll
  for (int j = 0; j < 8; ++j) { ps[j] = 0.f; as[j] = 0.f; }
#pragma unroll
  for (int s = 0; s < KS; ++s) {
    uint4 pv = ((const uint4*)(pbase + s * seg))[i];
    uint4 av = ((const uint4*)(abase + s * seg))[i];
    const unsigned int pw[4] = {pv.x, pv.y, pv.z, pv.w};
    const unsigned int aw[4] = {av.x, av.y, av.z, av.w};
#pragma unroll
    for (int q = 0; q < 4; ++q) {
      ps[2*q]   += bf2f((ushort)(pw[q] & 0xffff));
      ps[2*q+1] += bf2f((ushort)(pw[q] >> 16));
      as[2*q]   += bf2f((ushort)(aw[q] & 0xffff));
      as[2*q+1] += bf2f((ushort)(aw[q] >> 16));
    }
  }
  uint4 po, ao;
  unsigned int* pw = (unsigned int*)&po;
  unsigned int* aw = (unsigned int*)&ao;
#pragma unroll
  for (int q = 0; q < 4; ++q) {
    pw[q] = (unsigned int)f2bf(ps[2*q]) | ((unsigned int)f2bf(ps[2*q+1]) << 16);
    aw[q] = (unsigned int)f2bf(as[2*q]) | ((unsigned int)f2bf(as[2*q+1]) << 16);
  }
  ((uint4*)pbase)[i] = po;
  ((uint4*)abase)[i] = ao;
  uint4 z = {0u, 0u, 0u, 0u};
#pragma unroll
  for (int s = 1; s < NREP; ++s)
    ((uint4*)(abase + s * seg))[i] = z;
}

// K2: scatter-add 16 bf16 feats, 8 lanes/edge, 1 packed atomic each,
// into replica (e & 3) -> 4x less per-line RMW contention.
__global__ __launch_bounds__(256) void k2_scatter(
    const int* __restrict__ ei, const ushort* __restrict__ p1,
    ushort* __restrict__ abase, size_t seg, int nE) {
  long long tid = (long long)blockIdx.x * 256 + threadIdx.x;
  if (tid >= (long long)nE * 8) return;
  int e = (int)(tid >> 3), f = (int)(tid & 7);
  int s = ei[e], d = ei[nE + e];
  int rep = e & (NREP - 1);
  unsigned int v = ((const unsigned int*)p1)[(size_t)s * 8 + f];
  pk_atomic_bf16((unsigned int*)(abase + rep * seg) + (size_t)d * 8 + f, v);
}

// K3: sum 4 agg replicas (fp32), ELU, dual 16x7 projection; p2 bf16[8],
// out replica 0 init bf16[8], out replicas 1..3 zeroed.
__global__ __launch_bounds__(256) void k3_l2(
    const ushort* __restrict__ abase, size_t seg,
    const float* __restrict__ w_root2, const float* __restrict__ w_rel2,
    const float* __restrict__ b2,
    ushort* __restrict__ p2, ushort* __restrict__ out_bf, int n) {
  int i = blockIdx.x * 256 + threadIdx.x;
  if (i >= n) return;
  float h[HID];
#pragma unroll
  for (int k = 0; k < HID; ++k) h[k] = 0.f;
#pragma unroll
  for (int rep = 0; rep < NREP; ++rep) {
    const uint4* arow = (const uint4*)(abase + rep * seg + (size_t)i * HID);
#pragma unroll
    for (int half = 0; half < 2; ++half) {
      uint4 v = arow[half];
      const unsigned int w[4] = {v.x, v.y, v.z, v.w};
#pragma unroll
      for (int q = 0; q < 4; ++q) {
        h[half*8 + 2*q]     += bf2f((ushort)(w[q] & 0xffff));
        h[half*8 + 2*q + 1] += bf2f((ushort)(w[q] >> 16));
      }
    }
  }
#pragma unroll
  for (int k = 0; k < HID; ++k)
    h[k] = h[k] > 0.f ? h[k] : expm1f(h[k]);

  float sr[8], so[8];
#pragma unroll
  for (int c = 0; c < 8; ++c) { sr[c] = 0.f; so[c] = 0.f; }
#pragma unroll
  for (int c = 0; c < NCLS; ++c) {
    float a = 0.f, b = b2[c];
#pragma unroll
    for (int k = 0; k < HID; ++k) {
      a = fmaf(h[k], w_rel2[k * NCLS + c], a);
      b = fmaf(h[k], w_root2[k * NCLS + c], b);
    }
    sr[c] = a; so[c] = b;
  }
  uint4 pv, ov;
  unsigned int* pw = (unsigned int*)&pv;
  unsigned int* ow = (unsigned int*)&ov;
#pragma unroll
  for (int q = 0; q < 4; ++q) {
    pw[q] = (unsigned int)f2bf(sr[2*q]) | ((unsigned int)f2bf(sr[2*q+1]) << 16);
    ow[q] = (unsigned int)f2bf(so[2*q]) | ((unsigned int)f2bf(so[2*q+1]) << 16);
  }
  ((uint4*)(p2     + (size_t)i * 8))[0] = pv;
  ((uint4*)(out_bf + (size_t)i * 8))[0] = ov;
  uint4 z = {0u, 0u, 0u, 0u};
#pragma unroll
  for (int rep = 1; rep < NREP; ++rep)
    ((uint4*)(out_bf + (size_t)rep * n * 8 + (size_t)i * 8))[0] = z;
}

// K4: scatter-add 8 bf16 logits, 4 lanes/edge, packed atomics into replica e&3.
__global__ __launch_bounds__(256) void k4_scatter(
    const int* __restrict__ ei, const ushort* __restrict__ p2,
    ushort* __restrict__ out_bf, int n, int nE) {
  long long tid = (long long)blockIdx.x * 256 + threadIdx.x;
  if (tid >= (long long)nE * 4) return;
  int e = (int)(tid >> 2), f = (int)(tid & 3);
  int s = ei[e], d = ei[nE + e];
  int rep = e & (NREP - 1);
  unsigned int v = ((const unsigned int*)p2)[(size_t)s * 4 + f];
  pk_atomic_bf16((unsigned int*)(out_bf + (size_t)rep * n * 8) + (size_t)d * 4 + f, v);
}

// K5: sum 4 logit replicas (fp32), log_softmax -> fp32 d_out.
__global__ __launch_bounds__(256) void k5_lsm(
    const ushort* __restrict__ out_bf, float* __restrict__ out, int n) {
  int i = blockIdx.x * 256 + threadIdx.x;
  if (i >= n) return;
  float v[8];
#pragma unroll
  for (int c = 0; c < 8; ++c) v[c] = 0.f;
#pragma unroll
  for (int rep = 0; rep < NREP; ++rep) {
    uint4 rv = ((const uint4*)(out_bf + (size_t)rep * n * 8 + (size_t)i * 8))[0];
    const unsigned int w[4] = {rv.x, rv.y, rv.z, rv.w};
#pragma unroll
    for (int q = 0; q < 4; ++q) {
      v[2*q]   += bf2f((ushort)(w[q] & 0xffff));
      v[2*q+1] += bf2f((ushort)(w[q] >> 16));
    }
  }
  float m = v[0];
#pragma unroll
  for (int c = 1; c < NCLS; ++c) m = fmaxf(m, v[c]);
  float s = 0.f;
#pragma unroll
  for (int c = 0; c < NCLS; ++c) s += expf(v[c] - m);
  float l = logf(s);
  float* o = out + (size_t)i * NCLS;
#pragma unroll
  for (int c = 0; c < NCLS; ++c) o[c] = v[c] - m - l;
}

extern "C" void kernel_launch(void* const* d_in, const int* in_sizes, int n_in,
                              void* d_out, int out_size, void* d_ws, size_t ws_size,
                              hipStream_t stream) {
  const float* x       = (const float*)d_in[0];
  const int*   ei      = (const int*)  d_in[1];
  const float* w_root1 = (const float*)d_in[2];
  const float* w_rel1  = (const float*)d_in[3];
  const float* b_rel1  = (const float*)d_in[4];
  const float* w_root2 = (const float*)d_in[5];
  const float* w_rel2  = (const float*)d_in[6];
  const float* b_rel2  = (const float*)d_in[7];
  float* out = (float*)d_out;

  int n  = in_sizes[0] / FIN;   // 100000
  int nE = in_sizes[1] / 2;     // 3200000

  size_t seg = (size_t)n * HID;             // bf16 elems per slice/replica buffer
  char* ws = (char*)d_ws;
  ushort* pbase = (ushort*)ws;                             // KS*seg bf16
  ushort* abase = pbase + KS * seg;                        // KS*seg bf16 (-> replicas)
  ushort* p2    = abase + KS * seg;                        // n*8 bf16
  ushort* outbf = p2 + (size_t)n * 8;                      // NREP * n*8 bf16
  ushort* wT    = outbf + (size_t)NREP * n * 8;            // 32*1440 bf16

  int nbN = (n + 255) / 256;

  k_wt<<<(32 * KPAD + 255) / 256, 256, 0, stream>>>(w_root1, w_rel1, wT);

  dim3 g1((n + BM - 1) / BM, KS);
  k1_mfma<<<g1, 256, 0, stream>>>(x, wT, b_rel1, pbase, abase, seg, n);
  int n8 = n * HID / 8;
  k_reduce<<<(n8 + 255) / 256, 256, 0, stream>>>(pbase, abase, seg, n8);

  long long t2 = (long long)nE * 8;
  k2_scatter<<<(int)((t2 + 255) / 256), 256, 0, stream>>>(ei, pbase, abase, seg, nE);

  k3_l2<<<nbN, 256, 0, stream>>>(abase, seg, w_root2, w_rel2, b_rel2, p2, outbf, n);

  long long t4 = (long long)nE * 4;
  k4_scatter<<<(int)((t4 + 255) / 256), 256, 0, stream>>>(ei, p2, outbf, n, nE);

  k5_lsm<<<nbN, 256, 0, stream>>>(outbf, out, n);
}

// Round 10
// 479.810 us; speedup vs baseline: 1.0044x; 1.0044x over previous
//
#include <hip/hip_runtime.h>
#include <hip/hip_bf16.h>
#include <math.h>
#include <string.h>

#define FIN  1433
#define HID  16
#define NCLS 7
#define BM   128
#define BK   32
#define KS   4
#define KT_TOTAL 45            // ceil(1433/32)
#define KPAD (KT_TOTAL * BK)   // 1440

typedef __attribute__((ext_vector_type(8))) short bf16x8;
typedef __attribute__((ext_vector_type(4))) float f32x4;

__device__ inline float bf2f(ushort u) {
  unsigned int t = ((unsigned int)u) << 16;
  return __uint_as_float(t);
}
__device__ inline ushort f2bf(float f) {
  __hip_bfloat16 h = __float2bfloat16(f);
  return *(ushort*)&h;
}
__device__ inline void pk_atomic_bf16(void* addr, unsigned int data) {
  asm volatile("global_atomic_pk_add_bf16 %0, %1, off"
               :: "v"((unsigned long long)addr), "v"(data) : "memory");
}

// W prep: wT[c][k] bf16 (row stride KPAD); c<16 -> w_rel1, c>=16 -> w_root1.
__global__ __launch_bounds__(256) void k_wt(
    const float* __restrict__ w_root, const float* __restrict__ w_rel,
    ushort* __restrict__ wT) {
  int idx = blockIdx.x * 256 + threadIdx.x;
  if (idx >= 32 * KPAD) return;
  int c = idx / KPAD, k = idx % KPAD;
  float v = 0.f;
  if (k < FIN) v = (c < HID) ? w_rel[k * HID + c] : w_root[k * HID + (c - HID)];
  wT[idx] = f2bf(v);
}

// K1: split-K MFMA dual GEMM. LDS tiles are [row][32 bf16] with the 16B
// chunk index XOR-swizzled by s(row)=(row+(row>>2))&3 -> fragment reads
// and staged writes land <=2-way on banks (8-way without it).
__global__ __launch_bounds__(256) void k1_mfma(
    const float* __restrict__ x, const ushort* __restrict__ wT,
    const float* __restrict__ b_rel,
    ushort* __restrict__ pbase, ushort* __restrict__ abase,
    size_t seg, int n) {
  __shared__ ushort xs[2][BM * BK];   // 8 KB each
  __shared__ ushort wsh[2][32 * BK];  // 2 KB each

  const int tid  = threadIdx.x;
  const int lane = tid & 63;
  const int wave = tid >> 6;
  const int row0 = blockIdx.x * BM;
  const int slice = blockIdx.y;
  const int kt_beg = (KT_TOTAL * slice) / KS;
  const int kt_end = (KT_TOTAL * (slice + 1)) / KS;

  f32x4 acc[2][2] = {};

  // staging geometry (thread-constant)
  const int t8  = tid >> 3;            // 0..31
  const int q4  = tid & 7;             // float4 index within 32-k row
  const int sw  = (t8 + (t8 >> 2)) & 3;            // write swizzle
  const int cw  = (((q4 >> 1) ^ sw) * 8) + (q4 & 1) * 4;  // ushort offset in row

  float4  xr4[4];
  ushort4 wr;

  auto load_tile = [&](int kt) {
    const int k0 = kt * BK;
    const int gk0 = k0 + q4 * 4;
    if (k0 + BK <= FIN) {
#pragma unroll
      for (int i = 0; i < 4; ++i) {
        int gr = row0 + i * 32 + t8;
        if (gr < n) __builtin_memcpy(&xr4[i], &x[(size_t)gr * FIN + gk0], 16);
        else        xr4[i] = make_float4(0.f, 0.f, 0.f, 0.f);
      }
    } else {
#pragma unroll
      for (int i = 0; i < 4; ++i) {
        int gr = row0 + i * 32 + t8;
        float4 v = make_float4(0.f, 0.f, 0.f, 0.f);
        if (gr < n) {
          const float* xp = &x[(size_t)gr * FIN];
          if (gk0 + 0 < FIN) v.x = xp[gk0 + 0];
          if (gk0 + 1 < FIN) v.y = xp[gk0 + 1];
          if (gk0 + 2 < FIN) v.z = xp[gk0 + 2];
          if (gk0 + 3 < FIN) v.w = xp[gk0 + 3];
        }
        xr4[i] = v;
      }
    }
    wr = *(const ushort4*)&wT[(size_t)t8 * KPAD + k0 + q4 * 4];
  };

  auto store_stage = [&](int b) {
#pragma unroll
    for (int i = 0; i < 4; ++i) {
      ushort4 p;
      p.x = f2bf(xr4[i].x); p.y = f2bf(xr4[i].y);
      p.z = f2bf(xr4[i].z); p.w = f2bf(xr4[i].w);
      *(ushort4*)&xs[b][(i * 32 + t8) * BK + cw] = p;
    }
    *(ushort4*)&wsh[b][t8 * BK + cw] = wr;
  };

  const int m = lane & 15, o = lane >> 4;
  const int sm = (m + (m >> 2)) & 3;      // read swizzle (same for row m, 16+m, wave*32+mf*16+m)
  const int ch = (o ^ sm) * 8;            // swizzled 16B chunk -> ushort offset

  auto do_mfma = [&](int b) {
    bf16x8 b0 = *(const bf16x8*)&wsh[b][(m)      * BK + ch];
    bf16x8 b1 = *(const bf16x8*)&wsh[b][(16 + m) * BK + ch];
#pragma unroll
    for (int mf = 0; mf < 2; ++mf) {
      bf16x8 a = *(const bf16x8*)&xs[b][(wave * 32 + mf * 16 + m) * BK + ch];
      acc[mf][0] = __builtin_amdgcn_mfma_f32_16x16x32_bf16(a, b0, acc[mf][0], 0, 0, 0);
      acc[mf][1] = __builtin_amdgcn_mfma_f32_16x16x32_bf16(a, b1, acc[mf][1], 0, 0, 0);
    }
  };

  load_tile(kt_beg);
  store_stage(0);
  __syncthreads();
  for (int t = kt_beg; t < kt_end; ++t) {
    const int b = (t - kt_beg) & 1;
    const bool more = (t + 1) < kt_end;
    if (more) load_tile(t + 1);
    do_mfma(b);
    if (more) store_stage(b ^ 1);
    __syncthreads();
  }

  ushort* __restrict__ p_out = pbase + (size_t)slice * seg;
  ushort* __restrict__ a_out = abase + (size_t)slice * seg;
  const float bv = (slice == 0) ? b_rel[m] : 0.f;
#pragma unroll
  for (int mf = 0; mf < 2; ++mf) {
#pragma unroll
    for (int j = 0; j < 4; ++j) {
      int gr = row0 + wave * 32 + mf * 16 + o * 4 + j;
      if (gr < n) {
        p_out[(size_t)gr * HID + m] = f2bf(acc[mf][0][j]);
        a_out[(size_t)gr * HID + m] = f2bf(acc[mf][1][j] + bv);
      }
    }
  }
}

// KR: sum KS bf16 partials into slice 0 (uint4 = 8 bf16 per thread).
__global__ __launch_bounds__(256) void k_reduce(
    ushort* __restrict__ pbase, ushort* __restrict__ abase,
    size_t seg, int n8) {
  int i = blockIdx.x * 256 + threadIdx.x;
  if (i >= n8) return;
  float ps[8], as[8];
#pragma unroll
  for (int j = 0; j < 8; ++j) { ps[j] = 0.f; as[j] = 0.f; }
#pragma unroll
  for (int s = 0; s < KS; ++s) {
    uint4 pv = ((const uint4*)(pbase + s * seg))[i];
    uint4 av = ((const uint4*)(abase + s * seg))[i];
    const unsigned int pw[4] = {pv.x, pv.y, pv.z, pv.w};
    const unsigned int aw[4] = {av.x, av.y, av.z, av.w};
#pragma unroll
    for (int q = 0; q < 4; ++q) {
      ps[2*q]   += bf2f((ushort)(pw[q] & 0xffff));
      ps[2*q+1] += bf2f((ushort)(pw[q] >> 16));
      as[2*q]   += bf2f((ushort)(aw[q] & 0xffff));
      as[2*q+1] += bf2f((ushort)(aw[q] >> 16));
    }
  }
  uint4 po, ao;
  unsigned int* pw = (unsigned int*)&po;
  unsigned int* aw = (unsigned int*)&ao;
#pragma unroll
  for (int q = 0; q < 4; ++q) {
    pw[q] = (unsigned int)f2bf(ps[2*q]) | ((unsigned int)f2bf(ps[2*q+1]) << 16);
    aw[q] = (unsigned int)f2bf(as[2*q]) | ((unsigned int)f2bf(as[2*q+1]) << 16);
  }
  ((uint4*)pbase)[i] = po;
  ((uint4*)abase)[i] = ao;
}

// K2: scatter-add 16 bf16 feats, 8 lanes/edge, 1 packed atomic each.
__global__ __launch_bounds__(256) void k2_scatter(
    const int* __restrict__ ei, const ushort* __restrict__ p1,
    ushort* __restrict__ agg, int nE) {
  long long tid = (long long)blockIdx.x * 256 + threadIdx.x;
  if (tid >= (long long)nE * 8) return;
  int e = (int)(tid >> 3), f = (int)(tid & 7);
  int s = ei[e], d = ei[nE + e];
  unsigned int v = ((const unsigned int*)p1)[(size_t)s * 8 + f];
  pk_atomic_bf16((unsigned int*)agg + (size_t)d * 8 + f, v);
}

// K3: ELU + dual 16x7 projection from bf16 agg; p2 bf16[8], out_bf init bf16[8].
__global__ __launch_bounds__(256) void k3_l2(
    const ushort* __restrict__ agg,
    const float* __restrict__ w_root2, const float* __restrict__ w_rel2,
    const float* __restrict__ b2,
    ushort* __restrict__ p2, ushort* __restrict__ out_bf, int n) {
  int i = blockIdx.x * 256 + threadIdx.x;
  if (i >= n) return;
  float h[HID];
  const uint4* arow = (const uint4*)(agg + (size_t)i * HID);
#pragma unroll
  for (int half = 0; half < 2; ++half) {
    uint4 v = arow[half];
    const unsigned int w[4] = {v.x, v.y, v.z, v.w};
#pragma unroll
    for (int q = 0; q < 4; ++q) {
      float t0 = bf2f((ushort)(w[q] & 0xffff));
      float t1 = bf2f((ushort)(w[q] >> 16));
      h[half*8 + 2*q]     = t0 > 0.f ? t0 : expm1f(t0);
      h[half*8 + 2*q + 1] = t1 > 0.f ? t1 : expm1f(t1);
    }
  }
  float sr[8], so[8];
#pragma unroll
  for (int c = 0; c < 8; ++c) { sr[c] = 0.f; so[c] = 0.f; }
#pragma unroll
  for (int c = 0; c < NCLS; ++c) {
    float a = 0.f, b = b2[c];
#pragma unroll
    for (int k = 0; k < HID; ++k) {
      a = fmaf(h[k], w_rel2[k * NCLS + c], a);
      b = fmaf(h[k], w_root2[k * NCLS + c], b);
    }
    sr[c] = a; so[c] = b;
  }
  uint4 pv, ov;
  unsigned int* pw = (unsigned int*)&pv;
  unsigned int* ow = (unsigned int*)&ov;
#pragma unroll
  for (int q = 0; q < 4; ++q) {
    pw[q] = (unsigned int)f2bf(sr[2*q]) | ((unsigned int)f2bf(sr[2*q+1]) << 16);
    ow[q] = (unsigned int)f2bf(so[2*q]) | ((unsigned int)f2bf(so[2*q+1]) << 16);
  }
  ((uint4*)(p2     + (size_t)i * 8))[0] = pv;
  ((uint4*)(out_bf + (size_t)i * 8))[0] = ov;
}

// K4: scatter-add 8 bf16 logits, 4 lanes/edge, packed atomics.
__global__ __launch_bounds__(256) void k4_scatter(
    const int* __restrict__ ei, const ushort* __restrict__ p2,
    ushort* __restrict__ out_bf, int nE) {
  long long tid = (long long)blockIdx.x * 256 + threadIdx.x;
  if (tid >= (long long)nE * 4) return;
  int e = (int)(tid >> 2), f = (int)(tid & 3);
  int s = ei[e], d = ei[nE + e];
  unsigned int v = ((const unsigned int*)p2)[(size_t)s * 4 + f];
  pk_atomic_bf16((unsigned int*)out_bf + (size_t)d * 4 + f, v);
}

// K5: log_softmax from bf16 logits -> fp32 d_out.
__global__ __launch_bounds__(256) void k5_lsm(
    const ushort* __restrict__ out_bf, float* __restrict__ out, int n) {
  int i = blockIdx.x * 256 + threadIdx.x;
  if (i >= n) return;
  uint4 rv = ((const uint4*)(out_bf + (size_t)i * 8))[0];
  const unsigned int w[4] = {rv.x, rv.y, rv.z, rv.w};
  float v[8];
#pragma unroll
  for (int q = 0; q < 4; ++q) {
    v[2*q]   = bf2f((ushort)(w[q] & 0xffff));
    v[2*q+1] = bf2f((ushort)(w[q] >> 16));
  }
  float m = v[0];
#pragma unroll
  for (int c = 1; c < NCLS; ++c) m = fmaxf(m, v[c]);
  float s = 0.f;
#pragma unroll
  for (int c = 0; c < NCLS; ++c) s += expf(v[c] - m);
  float l = logf(s);
  float* o = out + (size_t)i * NCLS;
#pragma unroll
  for (int c = 0; c < NCLS; ++c) o[c] = v[c] - m - l;
}

extern "C" void kernel_launch(void* const* d_in, const int* in_sizes, int n_in,
                              void* d_out, int out_size, void* d_ws, size_t ws_size,
                              hipStream_t stream) {
  const float* x       = (const float*)d_in[0];
  const int*   ei      = (const int*)  d_in[1];
  const float* w_root1 = (const float*)d_in[2];
  const float* w_rel1  = (const float*)d_in[3];
  const float* b_rel1  = (const float*)d_in[4];
  const float* w_root2 = (const float*)d_in[5];
  const float* w_rel2  = (const float*)d_in[6];
  const float* b_rel2  = (const float*)d_in[7];
  float* out = (float*)d_out;

  int n  = in_sizes[0] / FIN;   // 100000
  int nE = in_sizes[1] / 2;     // 3200000

  size_t seg = (size_t)n * HID;             // bf16 elems per slice buffer
  char* ws = (char*)d_ws;
  ushort* pbase = (ushort*)ws;                             // KS*seg bf16
  ushort* abase = pbase + KS * seg;                        // KS*seg bf16
  ushort* p2    = abase + KS * seg;                        // n*8 bf16
  ushort* outbf = p2 + (size_t)n * 8;                      // n*8 bf16
  ushort* wT    = outbf + (size_t)n * 8;                   // 32*1440 bf16

  int nbN = (n + 255) / 256;

  k_wt<<<(32 * KPAD + 255) / 256, 256, 0, stream>>>(w_root1, w_rel1, wT);

  dim3 g1((n + BM - 1) / BM, KS);
  k1_mfma<<<g1, 256, 0, stream>>>(x, wT, b_rel1, pbase, abase, seg, n);
  int n8 = n * HID / 8;
  k_reduce<<<(n8 + 255) / 256, 256, 0, stream>>>(pbase, abase, seg, n8);

  long long t2 = (long long)nE * 8;
  k2_scatter<<<(int)((t2 + 255) / 256), 256, 0, stream>>>(ei, pbase, abase, nE);

  k3_l2<<<nbN, 256, 0, stream>>>(abase, w_root2, w_rel2, b_rel2, p2, outbf, n);

  long long t4 = (long long)nE * 4;
  k4_scatter<<<(int)((t4 + 255) / 256), 256, 0, stream>>>(ei, p2, outbf, nE);

  k5_lsm<<<nbN, 256, 0, stream>>>(outbf, out, n);
}